// Round 6
// baseline (21.653 us; speedup 1.0000x reference)
//
#include <hip/hip_runtime.h>

// DocumentBertScoringLoss: loss = MSE + MR + SIM over B=8192 fp32 vectors.
// MR term == mean over all (m,n) of max(0, 0.1 - |p_m - p_n|) (verified r1).
//
// Structure history (measured):
//   r1 two-kernel scalar-LDS pairwise: 18.4 us
//   r2 + 4-byte memset node: +39 us (fillBufferAligned fixed cost). DEAD END.
//   r3 cooperative grid.sync(): 104 us/dispatch. DEAD END.
//   r4 two-kernel, float4-LDS, 8 accums: 15.6 us.
//   r5 packed-f16 via __hmax2: COMPILE FAIL (no __hmax2 in ROCm hip_fp16.h).
// r6: same as r5 but packed f16 via _Float16 ext_vector + clang
//     __builtin_elementwise_{abs,max} (lowers to v_pk_* ops directly).
//     Triangle symmetry: sum = 2*sum_{m<n} + 0.1*B (diagonal analytic).

#define B_N 8192
#define THREADS 256
#define M_PER_THREAD 2
#define MB (THREADS * M_PER_THREAD)   // 512 m-rows per block
#define NXB (B_N / MB)                // 16 m-chunks
#define CHUNK 128                     // n's staged in LDS per block
#define NYB (B_N / CHUNK)             // 64 n-chunks
#define NBLOCKS (NXB * NYB)           // 1024 blocks

typedef _Float16 h2 __attribute__((ext_vector_type(2)));

__device__ __forceinline__ float block_reduce_sum(float v, float* sbuf) {
    #pragma unroll
    for (int off = 32; off > 0; off >>= 1)
        v += __shfl_down(v, off, 64);
    const int lane = threadIdx.x & 63;
    const int wave = threadIdx.x >> 6;
    if (lane == 0) sbuf[wave] = v;
    __syncthreads();
    if (threadIdx.x == 0) {
        float s = 0.f;
        #pragma unroll
        for (int w = 0; w < THREADS / 64; ++w) s += sbuf[w];
        sbuf[0] = s;
    }
    __syncthreads();
    const float r = sbuf[0];
    __syncthreads();
    return r;
}

__global__ void __launch_bounds__(THREADS)
pairwise_kernel(const float* __restrict__ p, const float* __restrict__ g,
                float* __restrict__ pairPartial,   // [NBLOCKS]
                float* __restrict__ linPartial) {  // [NXB*4]
    __shared__ float    s_f[CHUNK];
    __shared__ _Float16 s_h[CHUNK];
    __shared__ float    sbuf[THREADS / 64];

    const int tid = threadIdx.x;
    const int bx = blockIdx.x, by = blockIdx.y;
    const bool below = (by < 4 * bx);           // tile entirely n < m

    if (below && by != 0) {                     // no pairwise, no linear work
        if (tid == 0) pairPartial[by * NXB + bx] = 0.f;  // ws is poisoned: must write
        return;
    }

    const int m0 = bx * MB + tid;               // coalesced
    const int m1 = m0 + THREADS;
    const float pm0f = p[m0];
    const float pm1f = p[m1];

    if (by == 0) {                              // linear terms (block-uniform)
        const float gv0 = g[m0], gv1 = g[m1];
        const float d0 = pm0f - gv0, d1 = pm1f - gv1;
        float sq  = d0 * d0 + d1 * d1;
        float dot = pm0f * gv0 + pm1f * gv1;
        float npp = pm0f * pm0f + pm1f * pm1f;
        float ngg = gv0 * gv0 + gv1 * gv1;
        sq  = block_reduce_sum(sq, sbuf);
        dot = block_reduce_sum(dot, sbuf);
        npp = block_reduce_sum(npp, sbuf);
        ngg = block_reduce_sum(ngg, sbuf);
        if (tid == 0) {
            linPartial[bx * 4 + 0] = sq;
            linPartial[bx * 4 + 1] = dot;
            linPartial[bx * 4 + 2] = npp;
            linPartial[bx * 4 + 3] = ngg;
        }
    }

    if (below) {                                // by==0, bx>=1: linear only
        if (tid == 0) pairPartial[by * NXB + bx] = 0.f;
        return;
    }

    const int n0 = by * CHUNK;
    if (tid < CHUNK) {
        const float v = p[n0 + tid];
        s_f[tid] = v;
        s_h[tid] = (_Float16)v;
    }
    __syncthreads();

    float pairsum;
    if (by >= 4 * bx + 4) {
        // Full tile (all n > m): packed f16 (v_pk_sub/v_and/v_pk_max/v_pk_add).
        const h2* s2 = (const h2*)s_h;
        const _Float16 pm0s = (_Float16)pm0f;
        const _Float16 pm1s = (_Float16)pm1f;
        const h2 pm0 = {pm0s, pm0s};
        const h2 pm1 = {pm1s, pm1s};
        const h2 bias = {(_Float16)0.1f, (_Float16)0.1f};
        const h2 zero = {(_Float16)0.f, (_Float16)0.f};
        h2 a0a = zero, a0b = zero, a1a = zero, a1b = zero;
        #pragma unroll 8
        for (int j = 0; j < CHUNK / 2; j += 2) {
            const h2 va = s2[j];
            const h2 vb = s2[j + 1];
            a0a += __builtin_elementwise_max(bias - __builtin_elementwise_abs(pm0 - va), zero);
            a0b += __builtin_elementwise_max(bias - __builtin_elementwise_abs(pm0 - vb), zero);
            a1a += __builtin_elementwise_max(bias - __builtin_elementwise_abs(pm1 - va), zero);
            a1b += __builtin_elementwise_max(bias - __builtin_elementwise_abs(pm1 - vb), zero);
        }
        const h2 s01 = (a0a + a0b) + (a1a + a1b);
        pairsum = (float)s01.x + (float)s01.y;
    } else {
        // Diagonal-band tile: f32, per-thread loop starts just past n == m.
        float a0 = 0.f, a1 = 0.f;
        const int js0 = max(0, m0 - n0 + 1);
        for (int j = js0; j < CHUNK; ++j)
            a0 += fmaxf(0.f, 0.1f - fabsf(pm0f - s_f[j]));
        const int js1 = max(0, m1 - n0 + 1);
        for (int j = js1; j < CHUNK; ++j)
            a1 += fmaxf(0.f, 0.1f - fabsf(pm1f - s_f[j]));
        pairsum = a0 + a1;
    }

    const float s = block_reduce_sum(pairsum, sbuf);
    if (tid == 0) pairPartial[by * NXB + bx] = s;
}

__global__ void __launch_bounds__(THREADS)
finalize_kernel(const float* __restrict__ pairPartial,
                const float* __restrict__ linPartial,
                float* __restrict__ out) {
    __shared__ float sbuf[THREADS / 64];

    float tri = 0.f;
    #pragma unroll
    for (int k = 0; k < NBLOCKS / THREADS; ++k)
        tri += pairPartial[k * THREADS + threadIdx.x];
    tri = block_reduce_sum(tri, sbuf);

    float lv[4];
    #pragma unroll
    for (int k = 0; k < 4; ++k) {
        float v = 0.f;
        if (threadIdx.x < NXB) v = linPartial[threadIdx.x * 4 + k];
        lv[k] = block_reduce_sum(v, sbuf);
    }

    if (threadIdx.x == 0) {
        const float mse = lv[0] / (float)B_N;
        const float mr_total = 2.f * tri + 0.1f * (float)B_N;   // diagonal analytic
        const float mrm = mr_total / ((float)B_N * (float)B_N);
        const float denom = fmaxf(sqrtf(lv[2]) * sqrtf(lv[3]), 1e-8f);
        const float sim = 1.f - lv[1] / denom;
        out[0] = mse + mrm + sim;               // alpha = beta = gamma = 1
    }
}

extern "C" void kernel_launch(void* const* d_in, const int* in_sizes, int n_in,
                              void* d_out, int out_size, void* d_ws, size_t ws_size,
                              hipStream_t stream) {
    const float* p = (const float*)d_in[0];
    const float* g = (const float*)d_in[1];
    float* pairPartial = (float*)d_ws;            // 1024 floats, all rewritten each call
    float* linPartial  = (float*)d_ws + NBLOCKS;  // 64 floats, all rewritten each call

    dim3 grid(NXB, NYB);
    pairwise_kernel<<<grid, THREADS, 0, stream>>>(p, g, pairPartial, linPartial);
    finalize_kernel<<<1, THREADS, 0, stream>>>(pairPartial, linPartial, (float*)d_out);
}

// Round 7
// 14.811 us; speedup vs baseline: 1.4620x; 1.4620x over previous
//
#include <hip/hip_runtime.h>

// DocumentBertScoringLoss: loss = MSE + MR + SIM over B=8192 fp32 vectors.
// MR term == mean over all (m,n) of max(0, 0.1 - |p_m - p_n|) (verified r1).
// Identity used here:  sum max(0, 0.1-|d|)  =  0.1*B^2 - sum min(|d|, 0.1)
// (diagonal handled exactly by the f32 constant term; min term is branch-free).
//
// Structure history (measured):
//   r1 two-kernel scalar-LDS pairwise: 18.4 us
//   r2 + 4-byte memset node: +39 us (fillBufferAligned fixed cost). DEAD END.
//   r3 cooperative grid.sync(): 104 us/dispatch. DEAD END.
//   r4 two-kernel, float4-LDS f32, 8 accums, uniform: 15.6 us.
//   r6 triangle + diagonal-band divergent tiles: 21.7 us. DEAD END —
//      divergent stragglers beat the 1.9x work saving. Uniformity wins.
// r7: uniform full-square, packed-f16 min-trick (2 inst/pair), h8 LDS reads.

#define B_N 8192
#define THREADS 256
#define M_PER_THREAD 2
#define MB (THREADS * M_PER_THREAD)   // 512 m-rows per block
#define NXB (B_N / MB)                // 16 m-chunks
#define CHUNK 128                     // n's staged in LDS per block
#define NYB (B_N / CHUNK)             // 64 n-chunks
#define NBLOCKS (NXB * NYB)           // 1024 blocks = 4/CU -> 16 waves/CU

typedef _Float16 h8 __attribute__((ext_vector_type(8)));

__device__ __forceinline__ float block_reduce_sum(float v, float* sbuf) {
    #pragma unroll
    for (int off = 32; off > 0; off >>= 1)
        v += __shfl_down(v, off, 64);
    const int lane = threadIdx.x & 63;
    const int wave = threadIdx.x >> 6;
    if (lane == 0) sbuf[wave] = v;
    __syncthreads();
    if (threadIdx.x == 0) {
        float s = 0.f;
        #pragma unroll
        for (int w = 0; w < THREADS / 64; ++w) s += sbuf[w];
        sbuf[0] = s;
    }
    __syncthreads();
    const float r = sbuf[0];
    __syncthreads();
    return r;
}

__global__ void __launch_bounds__(THREADS)
pairwise_kernel(const float* __restrict__ p, const float* __restrict__ g,
                float* __restrict__ pairPartial,   // [NBLOCKS]
                float* __restrict__ linPartial) {  // [NXB*4]
    __shared__ alignas(16) _Float16 s_h[CHUNK];
    __shared__ float sbuf[THREADS / 64];

    const int tid = threadIdx.x;
    const int bx = blockIdx.x, by = blockIdx.y;
    const int m0 = bx * MB + tid;               // coalesced
    const int m1 = m0 + THREADS;
    const float pm0f = p[m0];
    const float pm1f = p[m1];

    if (tid < CHUNK) s_h[tid] = (_Float16)p[by * CHUNK + tid];
    __syncthreads();

    // Branch-free packed-f16 loop: per h8 and per row,
    // acc += min(|pm - v|, 0.1)  ->  pk_sub, and(abs), pk_min, pk_add.
    const h8* s8 = (const h8*)s_h;
    const _Float16 pm0s = (_Float16)pm0f;
    const _Float16 pm1s = (_Float16)pm1f;
    const h8 pm0 = {pm0s, pm0s, pm0s, pm0s, pm0s, pm0s, pm0s, pm0s};
    const h8 pm1 = {pm1s, pm1s, pm1s, pm1s, pm1s, pm1s, pm1s, pm1s};
    const _Float16 bs = (_Float16)0.1f;
    const h8 bias = {bs, bs, bs, bs, bs, bs, bs, bs};
    h8 acc0 = {0, 0, 0, 0, 0, 0, 0, 0};
    h8 acc1 = {0, 0, 0, 0, 0, 0, 0, 0};
    #pragma unroll
    for (int j = 0; j < CHUNK / 8; ++j) {       // 16 x ds_read_b128 (broadcast)
        const h8 v = s8[j];
        acc0 += __builtin_elementwise_min(__builtin_elementwise_abs(pm0 - v), bias);
        acc1 += __builtin_elementwise_min(__builtin_elementwise_abs(pm1 - v), bias);
    }
    float minsum = 0.f;
    #pragma unroll
    for (int k = 0; k < 8; ++k)
        minsum += (float)acc0[k] + (float)acc1[k];

    const float s = block_reduce_sum(minsum, sbuf);
    if (tid == 0) pairPartial[by * NXB + bx] = s;

    if (by == 0) {                              // linear terms (block-uniform, f32 exact)
        const float gv0 = g[m0], gv1 = g[m1];
        const float d0 = pm0f - gv0, d1 = pm1f - gv1;
        float sq  = d0 * d0 + d1 * d1;
        float dot = pm0f * gv0 + pm1f * gv1;
        float npp = pm0f * pm0f + pm1f * pm1f;
        float ngg = gv0 * gv0 + gv1 * gv1;
        sq  = block_reduce_sum(sq, sbuf);
        dot = block_reduce_sum(dot, sbuf);
        npp = block_reduce_sum(npp, sbuf);
        ngg = block_reduce_sum(ngg, sbuf);
        if (tid == 0) {
            linPartial[bx * 4 + 0] = sq;
            linPartial[bx * 4 + 1] = dot;
            linPartial[bx * 4 + 2] = npp;
            linPartial[bx * 4 + 3] = ngg;
        }
    }
}

__global__ void __launch_bounds__(THREADS)
finalize_kernel(const float* __restrict__ pairPartial,
                const float* __restrict__ linPartial,
                float* __restrict__ out) {
    __shared__ float sbuf[THREADS / 64];

    float minsum = 0.f;
    #pragma unroll
    for (int k = 0; k < NBLOCKS / THREADS; ++k)
        minsum += pairPartial[k * THREADS + threadIdx.x];
    minsum = block_reduce_sum(minsum, sbuf);

    float lv[4];
    #pragma unroll
    for (int k = 0; k < 4; ++k) {
        float v = 0.f;
        if (threadIdx.x < NXB) v = linPartial[threadIdx.x * 4 + k];
        lv[k] = block_reduce_sum(v, sbuf);
    }

    if (threadIdx.x == 0) {
        const float mse = lv[0] / (float)B_N;
        const float mrm = 0.1f - minsum / ((float)B_N * (float)B_N);
        const float denom = fmaxf(sqrtf(lv[2]) * sqrtf(lv[3]), 1e-8f);
        const float sim = 1.f - lv[1] / denom;
        out[0] = mse + mrm + sim;               // alpha = beta = gamma = 1
    }
}

extern "C" void kernel_launch(void* const* d_in, const int* in_sizes, int n_in,
                              void* d_out, int out_size, void* d_ws, size_t ws_size,
                              hipStream_t stream) {
    const float* p = (const float*)d_in[0];
    const float* g = (const float*)d_in[1];
    float* pairPartial = (float*)d_ws;            // 1024 floats, all rewritten each call
    float* linPartial  = (float*)d_ws + NBLOCKS;  // 64 floats, all rewritten each call

    dim3 grid(NXB, NYB);
    pairwise_kernel<<<grid, THREADS, 0, stream>>>(p, g, pairPartial, linPartial);
    finalize_kernel<<<1, THREADS, 0, stream>>>(pairPartial, linPartial, (float*)d_out);
}